// Round 3
// baseline (161.312 us; speedup 1.0000x reference)
//
#include <hip/hip_runtime.h>
#include <stdint.h>

#define DM 1024
#define LS 2048
#define RMS_EPS 1.1920928955078125e-07f
#define S2 0.0029296875f   // BC_SCALE^2 = 3/1024, exact in fp32

typedef __attribute__((ext_vector_type(8))) short bf16x8;
typedef __attribute__((ext_vector_type(4))) float f32x4;

__device__ __forceinline__ unsigned short f2bf(float f) {
  uint32_t u = __builtin_bit_cast(uint32_t, f);
  u += 0x7FFFu + ((u >> 16) & 1u);   // round-to-nearest-even
  return (unsigned short)(u >> 16);
}

// ---------------------------------------------------------------------------
// K0: pack B (64x1024) and C (64x1024) fp32 -> stacked bf16 [128][1024]
// ---------------------------------------------------------------------------
__global__ __launch_bounds__(256) void k0_prep(const float* __restrict__ B,
                                               const float* __restrict__ C,
                                               unsigned short* __restrict__ Bbf) {
  int i4 = blockIdx.x * 256 + threadIdx.x;          // 0..32767 float4s
  const float4* src = (i4 < 16384) ? (const float4*)B : (const float4*)C;
  float4 v = src[i4 & 16383];
  ushort4 o;
  o.x = f2bf(v.x); o.y = f2bf(v.y); o.z = f2bf(v.z); o.w = f2bf(v.w);
  ((ushort4*)Bbf)[i4] = o;
}

// ---------------------------------------------------------------------------
// KG: BuCuT[b][l][128] = ([B;C] @ u[b])^T as a proper tiled GEMM.
// grid (32,4)=128 blocks, block 512 (8 waves).  Tile: M=128, N=64 l-cols,
// K=1024 in 16 steps of BK=64.  Fixes vs old k1:
//  - staging loads are row-contiguous 256B (u) / 128B (Bbf) segments
//  - A (Bbf) staged in LDS with XOR swizzle (was scattered global per MFMA)
//  - register prefetch: step kk+1 global loads issued before compute of kk
// Wave w: rows [64*(w>>2),+64) x cols [16*(w&3),+16); acc[4] f32x4.
// ---------------------------------------------------------------------------
__global__ __launch_bounds__(512) void kg(const float* __restrict__ u,
                                          const unsigned short* __restrict__ Bbf,
                                          float* __restrict__ BuCuT) {
  const int b   = blockIdx.y;
  const int l0  = blockIdx.x * 64;
  const int tid = threadIdx.x;
  const int lane = tid & 63;
  const int w    = tid >> 6;
  const float* ub = u + (size_t)b * DM * LS;

  __shared__ bf16x8 At[128][8];   // [row][col16 ^ (row&7)], 16 KB
  __shared__ float  Ut[64][68];   // fp32 u-tile [k][l], pad 68 (16B-aligned rows)

  const int nn = lane & 15, q = lane >> 4;
  const int wr = w >> 2, wc = w & 3;

  bf16x8 arg[2]; float4 urg[2];

  auto LOAD = [&](int kk) {
    #pragma unroll
    for (int j = 0; j < 2; ++j) {
      int id = tid + 512*j;
      arg[j] = *(const bf16x8*)(Bbf + (size_t)(id >> 3) * DM + 64*kk + 8*(id & 7));
    }
    #pragma unroll
    for (int j = 0; j < 2; ++j) {
      int id = tid + 512*j;
      urg[j] = *(const float4*)(ub + (size_t)(64*kk + (id >> 4)) * LS + l0 + 4*(id & 15));
    }
  };
  auto WRITE = [&]() {
    #pragma unroll
    for (int j = 0; j < 2; ++j) {
      int id = tid + 512*j;
      At[id >> 3][(id & 7) ^ ((id >> 3) & 7)] = arg[j];
    }
    #pragma unroll
    for (int j = 0; j < 2; ++j) {
      int id = tid + 512*j;
      *(float4*)&Ut[id >> 4][4*(id & 15)] = urg[j];
    }
  };

  f32x4 acc[4] = {};
  LOAD(0); WRITE(); __syncthreads();

  for (int kk = 0; kk < 16; ++kk) {
    if (kk < 15) LOAD(kk + 1);            // in flight during compute
    #pragma unroll
    for (int c = 0; c < 2; ++c) {
      union { bf16x8 v; unsigned short s[8]; } bf;
      #pragma unroll
      for (int jj = 0; jj < 8; ++jj)
        bf.s[jj] = f2bf(Ut[32*c + 8*q + jj][16*wc + nn]);
      #pragma unroll
      for (int m = 0; m < 4; ++m) {
        const int row = 64*wr + 16*m + nn;
        bf16x8 af = At[row][(4*c + q) ^ (row & 7)];
        acc[m] = __builtin_amdgcn_mfma_f32_16x16x32_bf16(af, bf.v, acc[m], 0, 0, 0);
      }
    }
    __syncthreads();
    if (kk < 15) { WRITE(); __syncthreads(); }
  }

  // C/D: col = lane&15, row = 4*(lane>>4)+reg (proven layout)
  const int col = l0 + 16*wc + nn;
  float* ob = BuCuT + ((size_t)b * LS + col) * 128;
  #pragma unroll
  for (int m = 0; m < 4; ++m)
    *(f32x4*)(ob + 64*wr + 16*m + 4*q) = acc[m];
}

// ---------------------------------------------------------------------------
// KC: Kw-compute + conv(W=16) + u*D skip + RMSNorm(d) + store.
// grid (64,4)=256 blocks (1/CU), block 512 (8 waves).  Per block: 32 l-cols.
// Phase W: stage BuCuT rows [t0-16, t0+32) coalesced (25 KB).
// Phase K: Kw[t][j] = S2 * sum_n Cu[t][n] A^j[n] Bu[t-j][n], shfl reduce.
// Phase C: two t-halves of 16; y fp32 in LDS (unions with dead win buffer);
//          per-half RMS reduce (shfl + tiny LDS) then normalize + store.
// ---------------------------------------------------------------------------
__global__ __launch_bounds__(512) void kc(const float* __restrict__ u,
                                          const float* __restrict__ BuCuT,
                                          const float* __restrict__ A,
                                          const float* __restrict__ Dv,
                                          const float* __restrict__ nw,
                                          float* __restrict__ out) {
  const int b   = blockIdx.y;
  const int t0  = blockIdx.x * 32;
  const int tid = threadIdx.x;
  const int lane = tid & 63;
  const int w    = tid >> 6;
  const float* ub = u + (size_t)b * DM * LS;
  float* ob = out + (size_t)b * DM * LS;

  __shared__ __align__(16) char SMEM[66048];   // win[48][132]=25344 UNION y_l[16][1026]=65664
  float (*win)[132]  = (float (*)[132])SMEM;
  float (*y_l)[1026] = (float (*)[1026])SMEM;
  __shared__ float KwS[32][20];
  __shared__ float SSr[8][16];
  __shared__ float rsqv[16];

  { // ---- Phase W: stage window, fully coalesced ----
    #pragma unroll
    for (int j = 0; j < 3; ++j) {
      int id = tid + 512*j;                 // 1536 float4 chunks
      int r = id >> 5, c4 = id & 31;
      int g = t0 - 16 + r;
      float4 v = (g >= 0) ? *(const float4*)(BuCuT + ((size_t)b * LS + g) * 128 + 4*c4)
                          : make_float4(0.f, 0.f, 0.f, 0.f);
      *(float4*)&win[r][4*c4] = v;
    }
  }
  __syncthreads();

  { // ---- Phase K: Kw ----
    const int t = tid >> 4, p = tid & 15;
    float4 cu = *(const float4*)&win[16 + t][64 + 4*p];
    float4 aa = *(const float4*)(A + 4*p);
    float pw0 = cu.x * S2, pw1 = cu.y * S2, pw2 = cu.z * S2, pw3 = cu.w * S2;
    #pragma unroll
    for (int j = 0; j < 16; ++j) {
      float4 b4 = *(const float4*)&win[16 + t - j][4*p];
      float s = pw0*b4.x + pw1*b4.y + pw2*b4.z + pw3*b4.w;
      s += __shfl_xor(s, 1, 64);
      s += __shfl_xor(s, 2, 64);
      s += __shfl_xor(s, 4, 64);
      s += __shfl_xor(s, 8, 64);
      if (p == 0) KwS[t][j] = s;
      pw0 *= aa.x; pw1 *= aa.y; pw2 *= aa.z; pw3 *= aa.w;
    }
  }
  __syncthreads();

  // ---- Phase C: conv + RMS + store, two halves of 16 t ----
  const int cq = tid & 3;
  const int dr = tid >> 2;                  // 0..127
  #pragma unroll 1
  for (int h = 0; h < 2; ++h) {
    float ps[4] = {0.f, 0.f, 0.f, 0.f};
    const int cbase = t0 + 16*h - 16 + 4*cq;
    #pragma unroll 1
    for (int c = 0; c < 8; ++c) {
      const int d = dr + 128*c;
      const float* row = ub + (size_t)d * LS;
      float wrr[20];
      #pragma unroll
      for (int s5 = 0; s5 < 5; ++s5) {
        int g = cbase + 4*s5;
        float4 v = (g >= 0) ? *(const float4*)(row + g)
                            : make_float4(0.f, 0.f, 0.f, 0.f);
        wrr[4*s5+0] = v.x; wrr[4*s5+1] = v.y; wrr[4*s5+2] = v.z; wrr[4*s5+3] = v.w;
      }
      const float Dd = Dv[d];
      #pragma unroll
      for (int k = 0; k < 4; ++k) {
        const float* kwp = &KwS[16*h + 4*cq + k][0];   // broadcast LDS reads
        float acc = wrr[16 + k] * Dd;
        #pragma unroll
        for (int j = 0; j < 16; ++j)
          acc = fmaf(kwp[j], wrr[16 + k - j], acc);
        y_l[4*cq + k][d] = acc;
        ps[k] = fmaf(acc, acc, ps[k]);
      }
    }
    // reduce ps over dr (in-wave 16, then 8 waves via LDS)
    #pragma unroll
    for (int k = 0; k < 4; ++k) {
      ps[k] += __shfl_xor(ps[k], 4, 64);
      ps[k] += __shfl_xor(ps[k], 8, 64);
      ps[k] += __shfl_xor(ps[k], 16, 64);
      ps[k] += __shfl_xor(ps[k], 32, 64);
    }
    if (lane < 4)
      *(float4*)&SSr[w][4*lane] = make_float4(ps[0], ps[1], ps[2], ps[3]);
    __syncthreads();
    if (tid < 16) {
      float s = 0.f;
      #pragma unroll
      for (int ww = 0; ww < 8; ++ww) s += SSr[ww][tid];
      rsqv[tid] = rsqrtf(s * (1.f/1024.f) + RMS_EPS);
    }
    __syncthreads();
    #pragma unroll 1
    for (int c = 0; c < 8; ++c) {
      const int d = dr + 128*c;
      const float wn = nw[d];
      float4 o;
      o.x = y_l[4*cq + 0][d] * rsqv[4*cq + 0] * wn;
      o.y = y_l[4*cq + 1][d] * rsqv[4*cq + 1] * wn;
      o.z = y_l[4*cq + 2][d] * rsqv[4*cq + 2] * wn;
      o.w = y_l[4*cq + 3][d] * rsqv[4*cq + 3] * wn;
      *(float4*)(ob + (size_t)d * LS + t0 + 16*h + 4*cq) = o;
    }
    __syncthreads();   // y_l/SSr reused by next half
  }
}

// ---------------------------------------------------------------------------
extern "C" void kernel_launch(void* const* d_in, const int* in_sizes, int n_in,
                              void* d_out, int out_size, void* d_ws, size_t ws_size,
                              hipStream_t stream) {
  // inputs: [0]=L(int,1), [1]=u, [2]=A, [3]=B, [4]=C, [5]=D, [6]=norm_w
  const float* u  = (const float*)d_in[1];
  const float* A  = (const float*)d_in[2];
  const float* B  = (const float*)d_in[3];
  const float* C  = (const float*)d_in[4];
  const float* Dv = (const float*)d_in[5];
  const float* nw = (const float*)d_in[6];
  float* out = (float*)d_out;

  float* BuCuT = (float*)d_ws;                                        // 4 MB
  unsigned short* Bbf = (unsigned short*)((char*)d_ws + (4u << 20));  // 256 KB

  k0_prep<<<dim3(128),    dim3(256), 0, stream>>>(B, C, Bbf);
  kg     <<<dim3(32, 4),  dim3(512), 0, stream>>>(u, Bbf, BuCuT);
  kc     <<<dim3(64, 4),  dim3(512), 0, stream>>>(u, BuCuT, A, Dv, nw, out);
}

// Round 4
// 152.886 us; speedup vs baseline: 1.0551x; 1.0551x over previous
//
#include <hip/hip_runtime.h>
#include <stdint.h>

#define DM 1024
#define LS 2048
#define RMS_EPS 1.1920928955078125e-07f
#define S2 0.0029296875f   // BC_SCALE^2 = 3/1024, exact in fp32

typedef __attribute__((ext_vector_type(8))) short bf16x8;
typedef __attribute__((ext_vector_type(4))) float f32x4;

__device__ __forceinline__ unsigned short f2bf(float f) {
  uint32_t u = __builtin_bit_cast(uint32_t, f);
  u += 0x7FFFu + ((u >> 16) & 1u);   // round-to-nearest-even
  return (unsigned short)(u >> 16);
}

// ---------------------------------------------------------------------------
// K0: pack B (64x1024) and C (64x1024) fp32 -> stacked bf16 [128][1024]
// ---------------------------------------------------------------------------
__global__ __launch_bounds__(256) void k0_prep(const float* __restrict__ B,
                                               const float* __restrict__ C,
                                               unsigned short* __restrict__ Bbf) {
  int i4 = blockIdx.x * 256 + threadIdx.x;          // 0..32767 float4s
  const float4* src = (i4 < 16384) ? (const float4*)B : (const float4*)C;
  float4 v = src[i4 & 16383];
  ushort4 o;
  o.x = f2bf(v.x); o.y = f2bf(v.y); o.z = f2bf(v.z); o.w = f2bf(v.w);
  ((ushort4*)Bbf)[i4] = o;
}

// ---------------------------------------------------------------------------
// KG v3: BuCuT[b][l][128] = ([B;C] @ u[b])^T — LDS-free streaming MFMA.
// 512 blocks x 512 thr (2 blocks/CU, 16 waves/CU).  Block = (b, l-tile:32,
// M-half:64 rows of [B;C]).  Wave = one 16x16 output tile, K=1024 in 32
// MFMA steps.  No LDS, no barriers:
//  - A-frag: bf16x8 from Bbf global (256 KB, L2-resident, reused by all blocks)
//  - B-frag: 8 scalar u loads (16 nn-lanes = 64B segments; x8 reuse via L1/L2)
// Chunked XCD swizzle: mh-pairs and adjacent l-tiles share an XCD L2, so the
// 2x u read (B-half + C-half) is an L2 hit, HBM reads u once (32 MB).
// ---------------------------------------------------------------------------
__global__ __launch_bounds__(512) void kg(const float* __restrict__ u,
                                          const unsigned short* __restrict__ Bbf,
                                          float* __restrict__ BuCuT) {
  const int wg = blockIdx.x;                    // 0..511
  const int sw = (wg & 7) * 64 + (wg >> 3);     // chunked XCD swizzle (bijective)
  const int mh = sw & 1;
  const int lt = (sw >> 1) & 63;
  const int b  = sw >> 7;
  const int l0 = lt * 32;
  const int tid  = threadIdx.x;
  const int lane = tid & 63;
  const int w    = tid >> 6;
  const int nn = lane & 15, q = lane >> 4;
  const int wm = w >> 1, wn = w & 1;

  const float* ub = u + (size_t)b * DM * LS;
  const int row  = 64*mh + 16*wm + nn;          // [B;C] row for A-frag
  const int ucol = l0 + 16*wn + nn;             // l column for B-frag
  const float* ubase = ub + ucol;
  const unsigned short* abase = Bbf + (size_t)row * DM + 8*q;

  f32x4 acc = {};
  float uA[8], uB[8];
  bf16x8 aA, aB;

  auto LD = [&](int it, float* ur, bf16x8* ar) {
    const float* p = ubase + (size_t)(32*it + 8*q) * LS;
    #pragma unroll
    for (int jj = 0; jj < 8; ++jj) ur[jj] = p[(size_t)jj * LS];
    *ar = *(const bf16x8*)(abase + 32*it);
  };
  auto STEP = [&](const float* ur, const bf16x8* ar) {
    union { bf16x8 v; unsigned short s[8]; } t8;
    #pragma unroll
    for (int jj = 0; jj < 8; ++jj) t8.s[jj] = f2bf(ur[jj]);
    acc = __builtin_amdgcn_mfma_f32_16x16x32_bf16(*ar, t8.v, acc, 0, 0, 0);
  };

  LD(0, uA, &aA);
  LD(1, uB, &aB);
  #pragma unroll
  for (int it = 0; it < 16; ++it) {
    STEP(uA, &aA);
    if (it < 15) LD(2*it + 2, uA, &aA);
    STEP(uB, &aB);
    if (it < 15) LD(2*it + 3, uB, &aB);
  }

  // C/D layout (proven): col = lane&15 (=nn, l dim), row = 4*(lane>>4)+reg
  const int col = l0 + 16*wn + nn;
  float* ob = BuCuT + ((size_t)b * LS + col) * 128;
  *(f32x4*)(ob + 64*mh + 16*wm + 4*q) = acc;
}

// ---------------------------------------------------------------------------
// KC v4: Kw-compute (direct from global BuCuT) + conv(W=16) + u*D + RMS.
// 512 blocks x 512 thr (2 blocks/CU), t-tile 16, <2 KB LDS, 3 barriers.
// Phase K: thread (t:16, p:16, jh:2): Kw[t][j] = S2*sum_n Cu[t][n]A^j[n]Bu[t-j][n]
//          j in [8jh, 8jh+8), recurrence from A^(8jh); shfl-xor reduce over p.
//          BuCuT reads are L2-hot (4 MB, just written, same-XCD via swizzle).
// Phase C: thread (tg:4, dr:128): 8 d-chunks, y[8][4] in REGISTERS,
//          kw via broadcast LDS b128 reads per (c,k) (no 64-reg kw array).
// RMS: shfl over lane bits 2-5 + SSr[8][16] + rsqv.
// ---------------------------------------------------------------------------
__global__ __launch_bounds__(512) void kc(const float* __restrict__ u,
                                          const float* __restrict__ BuCuT,
                                          const float* __restrict__ A,
                                          const float* __restrict__ Dv,
                                          const float* __restrict__ nw,
                                          float* __restrict__ out) {
  const int wg = blockIdx.x;                    // 0..511
  const int sw = (wg & 7) * 64 + (wg >> 3);     // chunked XCD swizzle
  const int b  = sw >> 7;
  const int t0 = (sw & 127) * 16;
  const int tid  = threadIdx.x;
  const int lane = tid & 63;
  const int w    = tid >> 6;
  const float* ub = u + (size_t)b * DM * LS;
  float* ob = out + (size_t)b * DM * LS;

  __shared__ float KwS[16][20];
  __shared__ float SSr[8][16];
  __shared__ float rsqv[16];

  { // ---- Phase K ----
    const int t  = (tid >> 4) & 15;
    const int p  = tid & 15;
    const int jh = tid >> 8;                    // 0..1
    const float* bb = BuCuT + (size_t)b * LS * 128;
    const float4 cu = *(const float4*)(bb + (size_t)(t0 + t) * 128 + 64 + 4*p);
    const float4 aa = *(const float4*)(A + 4*p);
    float apx = 1.f, apy = 1.f, apz = 1.f, apw = 1.f;
    if (jh) {                                   // A^8 per component
      float a2x = aa.x*aa.x, a2y = aa.y*aa.y, a2z = aa.z*aa.z, a2w = aa.w*aa.w;
      float a4x = a2x*a2x,  a4y = a2y*a2y,  a4z = a2z*a2z,  a4w = a2w*a2w;
      apx = a4x*a4x; apy = a4y*a4y; apz = a4z*a4z; apw = a4w*a4w;
    }
    float pw0 = cu.x * S2 * apx;
    float pw1 = cu.y * S2 * apy;
    float pw2 = cu.z * S2 * apz;
    float pw3 = cu.w * S2 * apw;
    #pragma unroll
    for (int jj = 0; jj < 8; ++jj) {
      const int j = 8*jh + jj;
      const int g = t0 + t - j;
      float4 b4 = (g >= 0) ? *(const float4*)(bb + (size_t)g * 128 + 4*p)
                           : make_float4(0.f, 0.f, 0.f, 0.f);
      float s = pw0*b4.x + pw1*b4.y + pw2*b4.z + pw3*b4.w;
      s += __shfl_xor(s, 1, 64);
      s += __shfl_xor(s, 2, 64);
      s += __shfl_xor(s, 4, 64);
      s += __shfl_xor(s, 8, 64);
      if (p == 0) KwS[t][j] = s;
      pw0 *= aa.x; pw1 *= aa.y; pw2 *= aa.z; pw3 *= aa.w;
    }
  }
  __syncthreads();

  // ---- Phase C: conv + u*D, y in registers ----
  const int tg = tid & 3;
  const int dr = tid >> 2;                      // 0..127
  const int cbase = t0 - 16 + 4*tg;
  float y[8][4];
  float ps[4] = {0.f, 0.f, 0.f, 0.f};
  #pragma unroll 1
  for (int c = 0; c < 8; ++c) {
    const int d = dr + 128*c;
    const float* rowp = ub + (size_t)d * LS;
    float wr[20];
    #pragma unroll
    for (int s5 = 0; s5 < 5; ++s5) {
      int g = cbase + 4*s5;
      float4 v = (g >= 0) ? *(const float4*)(rowp + g)
                          : make_float4(0.f, 0.f, 0.f, 0.f);
      wr[4*s5+0] = v.x; wr[4*s5+1] = v.y; wr[4*s5+2] = v.z; wr[4*s5+3] = v.w;
    }
    const float Dd = Dv[d];
    #pragma unroll
    for (int k = 0; k < 4; ++k) {
      f32x4 kv0 = *(const f32x4*)&KwS[4*tg + k][0];   // broadcast b128 reads
      f32x4 kv1 = *(const f32x4*)&KwS[4*tg + k][4];
      f32x4 kv2 = *(const f32x4*)&KwS[4*tg + k][8];
      f32x4 kv3 = *(const f32x4*)&KwS[4*tg + k][12];
      float acc = wr[16 + k] * Dd;                    // skip connection u*D
      #pragma unroll
      for (int j = 0; j < 4; ++j)  acc = fmaf(kv0[j], wr[16 + k - j],      acc);
      #pragma unroll
      for (int j = 0; j < 4; ++j)  acc = fmaf(kv1[j], wr[16 + k - (j+4)],  acc);
      #pragma unroll
      for (int j = 0; j < 4; ++j)  acc = fmaf(kv2[j], wr[16 + k - (j+8)],  acc);
      #pragma unroll
      for (int j = 0; j < 4; ++j)  acc = fmaf(kv3[j], wr[16 + k - (j+12)], acc);
      y[c][k] = acc;
      ps[k] = fmaf(acc, acc, ps[k]);
    }
  }

  // ---- RMS reduce over d ----
  #pragma unroll
  for (int k = 0; k < 4; ++k) {
    ps[k] += __shfl_xor(ps[k], 4, 64);
    ps[k] += __shfl_xor(ps[k], 8, 64);
    ps[k] += __shfl_xor(ps[k], 16, 64);
    ps[k] += __shfl_xor(ps[k], 32, 64);
  }
  if (lane < 4)                                 // lane == tg holds t = 4*lane+k
    *(float4*)&SSr[w][4*lane] = make_float4(ps[0], ps[1], ps[2], ps[3]);
  __syncthreads();
  if (tid < 16) {
    float s = 0.f;
    #pragma unroll
    for (int ww = 0; ww < 8; ++ww) s += SSr[ww][tid];
    rsqv[tid] = rsqrtf(s * (1.f/1024.f) + RMS_EPS);
  }
  __syncthreads();

  // ---- normalize + store ----
  float rq[4];
  #pragma unroll
  for (int k = 0; k < 4; ++k) rq[k] = rsqv[4*tg + k];
  #pragma unroll 1
  for (int c = 0; c < 8; ++c) {
    const int d = dr + 128*c;
    const float wn2 = nw[d];
    float4 o;
    o.x = y[c][0] * rq[0] * wn2;
    o.y = y[c][1] * rq[1] * wn2;
    o.z = y[c][2] * rq[2] * wn2;
    o.w = y[c][3] * rq[3] * wn2;
    *(float4*)(ob + (size_t)d * LS + t0 + 4*tg) = o;
  }
}

// ---------------------------------------------------------------------------
extern "C" void kernel_launch(void* const* d_in, const int* in_sizes, int n_in,
                              void* d_out, int out_size, void* d_ws, size_t ws_size,
                              hipStream_t stream) {
  // inputs: [0]=L(int,1), [1]=u, [2]=A, [3]=B, [4]=C, [5]=D, [6]=norm_w
  const float* u  = (const float*)d_in[1];
  const float* A  = (const float*)d_in[2];
  const float* B  = (const float*)d_in[3];
  const float* C  = (const float*)d_in[4];
  const float* Dv = (const float*)d_in[5];
  const float* nw = (const float*)d_in[6];
  float* out = (float*)d_out;

  float* BuCuT = (float*)d_ws;                                        // 4 MB
  unsigned short* Bbf = (unsigned short*)((char*)d_ws + (4u << 20));  // 256 KB

  k0_prep<<<dim3(128), dim3(256), 0, stream>>>(B, C, Bbf);
  kg     <<<dim3(512), dim3(512), 0, stream>>>(u, Bbf, BuCuT);
  kc     <<<dim3(512), dim3(512), 0, stream>>>(u, BuCuT, A, Dv, nw, out);
}

// Round 5
// 136.640 us; speedup vs baseline: 1.1806x; 1.1189x over previous
//
#include <hip/hip_runtime.h>
#include <stdint.h>

#define DM 1024
#define LS 2048
#define RMS_EPS 1.1920928955078125e-07f
#define S2 0.0029296875f   // BC_SCALE^2 = 3/1024, exact in fp32

typedef __attribute__((ext_vector_type(8))) short bf16x8;
typedef __attribute__((ext_vector_type(4))) float f32x4;
typedef __attribute__((ext_vector_type(2))) unsigned int u32x2;

__device__ __forceinline__ unsigned short f2bf(float f) {
  uint32_t u = __builtin_bit_cast(uint32_t, f);
  u += 0x7FFFu + ((u >> 16) & 1u);   // round-to-nearest-even
  return (unsigned short)(u >> 16);
}

// ---------------------------------------------------------------------------
// K0: pack B (64x1024) and C (64x1024) fp32 -> stacked bf16 [128][1024]
// ---------------------------------------------------------------------------
__global__ __launch_bounds__(256) void k0_prep(const float* __restrict__ B,
                                               const float* __restrict__ C,
                                               unsigned short* __restrict__ Bbf) {
  int i4 = blockIdx.x * 256 + threadIdx.x;          // 0..32767 float4s
  const float4* src = (i4 < 16384) ? (const float4*)B : (const float4*)C;
  float4 v = src[i4 & 16383];
  ushort4 o;
  o.x = f2bf(v.x); o.y = f2bf(v.y); o.z = f2bf(v.z); o.w = f2bf(v.w);
  ((ushort4*)Bbf)[i4] = o;
}

// ---------------------------------------------------------------------------
// KG v5: LDS-staged dbuf GEMM at full machine width.
// 512 blocks (= (mh:2) x (lt:64) x (b:4), XCD-chunk-swizzled) x 256 thr
// (4 waves) -> 2 blocks/CU with independent barriers.
// Tile M=64 ([B;C] half mh), N=32 l-cols, BK=64, K=1024 (16 dbuf steps).
//  - u converted to bf16 ONCE at stage time (R3 converted 4x per use).
//  - u panels [k][16l] bf16: row stride 32 B == ds_read_b64_tr_b16's native
//    gather stride -> B-frag = 2 HW transpose reads, zero inner-loop VALU.
//    288 B k-group stride spreads the q-groups across banks (~conflict-free).
//  - A-tile At2[row][9 chunks] (144 B row): afrag = 1 ds_read_b128, <=2-way.
//  - register prefetch of step kk+1 issued before compute of kk (R3-proven).
// Inner loop/wave/step: 2 ds_read_b128 + 8 tr reads + 4 MFMA.  Rule #18:
// tr asm block carries its own lgkmcnt(0) + sched_barrier(0).
// ---------------------------------------------------------------------------
__global__ __launch_bounds__(256) void kg(const float* __restrict__ u,
                                          const unsigned short* __restrict__ Bbf,
                                          float* __restrict__ BuCuT) {
  const int wg = blockIdx.x;                    // 0..511
  const int sw = (wg & 7) * 64 + (wg >> 3);     // chunked XCD swizzle (bijective)
  const int b  = sw >> 7;
  const int lt = (sw >> 1) & 63;
  const int mh = sw & 1;
  const int l0 = lt * 32;
  const int tid  = threadIdx.x;
  const int lane = tid & 63;
  const int w    = tid >> 6;                    // 0..3
  const int nn = lane & 15, q = lane >> 4;
  const float* ub = u + (size_t)b * DM * LS;

  __shared__ __align__(16) bf16x8 At2[2][64][9];    // [buf][row][kch+pad] 18.4 KB
  __shared__ __align__(16) unsigned short Ut[2][2304]; // [buf][2 panels x 1152] 9.2 KB

  bf16x8 ar[2]; float4 urg[2];

  auto LOAD = [&](int kk) {
    #pragma unroll
    for (int h = 0; h < 2; ++h) {
      int id = tid + 256*h;                     // kch = id&7, row = id>>3
      ar[h] = *(const bf16x8*)(Bbf + (size_t)(64*mh + (id >> 3)) * DM + 64*kk + 8*(id & 7));
    }
    #pragma unroll
    for (int h = 0; h < 2; ++h) {
      int id = tid + 256*h;                     // lq = id&7, k = id>>3
      urg[h] = *(const float4*)(ub + (size_t)(64*kk + (id >> 3)) * LS + l0 + 4*(id & 7));
    }
  };
  auto WRITE = [&](int buf) {
    #pragma unroll
    for (int h = 0; h < 2; ++h) {
      int id = tid + 256*h;
      At2[buf][id >> 3][id & 7] = ar[h];
    }
    #pragma unroll
    for (int h = 0; h < 2; ++h) {
      int id = tid + 256*h;
      const int k = id >> 3, lq = id & 7;
      u32x2 pk;
      pk[0] = (unsigned)f2bf(urg[h].x) | ((unsigned)f2bf(urg[h].y) << 16);
      pk[1] = (unsigned)f2bf(urg[h].z) | ((unsigned)f2bf(urg[h].w) << 16);
      // panel (lq>>2), k-group (k>>3) stride 144 ushort, row (k&7) stride 16
      const int idx = (lq >> 2)*1152 + (k >> 3)*144 + (k & 7)*16 + 4*(lq & 3);
      *(u32x2*)&Ut[buf][idx] = pk;              // 8-B aligned
    }
  };

  f32x4 acc[2] = {};
  const unsigned ut_base = (unsigned)(uintptr_t)&Ut[0][0];

  auto COMPUTE = [&](int buf) {
    bf16x8 af0 = At2[buf][16*w + nn][q];        // k = 8q..8q+7
    bf16x8 af1 = At2[buf][16*w + nn][4 + q];    // k = 32+8q..
    const unsigned utb = ut_base + buf*4608 + 2*nn + q*288;
    unsigned a00 = utb;                         // n=0, kc=0
    unsigned a01 = utb + 4*288;                 // n=0, kc=1
    unsigned a10 = utb + 2304;                  // n=1, kc=0
    unsigned a11 = utb + 2304 + 4*288;          // n=1, kc=1
    u32x2 r0, r1, r2, r3, r4, r5, r6, r7;
    asm volatile(
      "ds_read_b64_tr_b16 %0, %8\n\t"
      "ds_read_b64_tr_b16 %1, %8 offset:128\n\t"
      "ds_read_b64_tr_b16 %2, %9\n\t"
      "ds_read_b64_tr_b16 %3, %9 offset:128\n\t"
      "ds_read_b64_tr_b16 %4, %10\n\t"
      "ds_read_b64_tr_b16 %5, %10 offset:128\n\t"
      "ds_read_b64_tr_b16 %6, %11\n\t"
      "ds_read_b64_tr_b16 %7, %11 offset:128\n\t"
      "s_waitcnt lgkmcnt(0)"
      : "=&v"(r0), "=&v"(r1), "=&v"(r2), "=&v"(r3),
        "=&v"(r4), "=&v"(r5), "=&v"(r6), "=&v"(r7)
      : "v"(a00), "v"(a01), "v"(a10), "v"(a11));
    __builtin_amdgcn_sched_barrier(0);          // rule #18: pin MFMA after wait
    union { u32x2 d[2]; bf16x8 v; } b00, b01, b10, b11;
    b00.d[0] = r0; b00.d[1] = r1;
    b01.d[0] = r2; b01.d[1] = r3;
    b10.d[0] = r4; b10.d[1] = r5;
    b11.d[0] = r6; b11.d[1] = r7;
    acc[0] = __builtin_amdgcn_mfma_f32_16x16x32_bf16(af0, b00.v, acc[0], 0, 0, 0);
    acc[0] = __builtin_amdgcn_mfma_f32_16x16x32_bf16(af1, b01.v, acc[0], 0, 0, 0);
    acc[1] = __builtin_amdgcn_mfma_f32_16x16x32_bf16(af0, b10.v, acc[1], 0, 0, 0);
    acc[1] = __builtin_amdgcn_mfma_f32_16x16x32_bf16(af1, b11.v, acc[1], 0, 0, 0);
  };

  LOAD(0); WRITE(0); __syncthreads();
  for (int kk = 0; kk < 16; ++kk) {
    if (kk < 15) LOAD(kk + 1);                  // in flight during compute
    COMPUTE(kk & 1);
    __syncthreads();
    if (kk < 15) { WRITE((kk + 1) & 1); __syncthreads(); }
  }

  // C/D layout (proven): col = lane&15 (l dim), row = 4*(lane>>4)+reg
  float* ob = BuCuT + (size_t)b * LS * 128;
  #pragma unroll
  for (int n = 0; n < 2; ++n)
    *(f32x4*)(ob + (size_t)(l0 + 16*n + nn) * 128 + 64*mh + 16*w + 4*q) = acc[n];
}

// ---------------------------------------------------------------------------
// KC v4 (unchanged, ~23 us): Kw direct from global BuCuT + conv + u*D + RMS.
// 512 blocks x 512 thr (2/CU), t-tile 16, <2 KB LDS, 3 barriers.
// ---------------------------------------------------------------------------
__global__ __launch_bounds__(512) void kc(const float* __restrict__ u,
                                          const float* __restrict__ BuCuT,
                                          const float* __restrict__ A,
                                          const float* __restrict__ Dv,
                                          const float* __restrict__ nw,
                                          float* __restrict__ out) {
  const int wg = blockIdx.x;                    // 0..511
  const int sw = (wg & 7) * 64 + (wg >> 3);     // chunked XCD swizzle
  const int b  = sw >> 7;
  const int t0 = (sw & 127) * 16;
  const int tid  = threadIdx.x;
  const int lane = tid & 63;
  const int w    = tid >> 6;
  const float* ub = u + (size_t)b * DM * LS;
  float* ob = out + (size_t)b * DM * LS;

  __shared__ float KwS[16][20];
  __shared__ float SSr[8][16];
  __shared__ float rsqv[16];

  { // ---- Phase K ----
    const int t  = (tid >> 4) & 15;
    const int p  = tid & 15;
    const int jh = tid >> 8;                    // 0..1
    const float* bb = BuCuT + (size_t)b * LS * 128;
    const float4 cu = *(const float4*)(bb + (size_t)(t0 + t) * 128 + 64 + 4*p);
    const float4 aa = *(const float4*)(A + 4*p);
    float apx = 1.f, apy = 1.f, apz = 1.f, apw = 1.f;
    if (jh) {                                   // A^8 per component
      float a2x = aa.x*aa.x, a2y = aa.y*aa.y, a2z = aa.z*aa.z, a2w = aa.w*aa.w;
      float a4x = a2x*a2x,  a4y = a2y*a2y,  a4z = a2z*a2z,  a4w = a2w*a2w;
      apx = a4x*a4x; apy = a4y*a4y; apz = a4z*a4z; apw = a4w*a4w;
    }
    float pw0 = cu.x * S2 * apx;
    float pw1 = cu.y * S2 * apy;
    float pw2 = cu.z * S2 * apz;
    float pw3 = cu.w * S2 * apw;
    #pragma unroll
    for (int jj = 0; jj < 8; ++jj) {
      const int j = 8*jh + jj;
      const int g = t0 + t - j;
      float4 b4 = (g >= 0) ? *(const float4*)(bb + (size_t)g * 128 + 4*p)
                           : make_float4(0.f, 0.f, 0.f, 0.f);
      float s = pw0*b4.x + pw1*b4.y + pw2*b4.z + pw3*b4.w;
      s += __shfl_xor(s, 1, 64);
      s += __shfl_xor(s, 2, 64);
      s += __shfl_xor(s, 4, 64);
      s += __shfl_xor(s, 8, 64);
      if (p == 0) KwS[t][j] = s;
      pw0 *= aa.x; pw1 *= aa.y; pw2 *= aa.z; pw3 *= aa.w;
    }
  }
  __syncthreads();

  // ---- Phase C: conv + u*D, y in registers ----
  const int tg = tid & 3;
  const int dr = tid >> 2;                      // 0..127
  const int cbase = t0 - 16 + 4*tg;
  float y[8][4];
  float ps[4] = {0.f, 0.f, 0.f, 0.f};
  #pragma unroll 1
  for (int c = 0; c < 8; ++c) {
    const int d = dr + 128*c;
    const float* rowp = ub + (size_t)d * LS;
    float wr[20];
    #pragma unroll
    for (int s5 = 0; s5 < 5; ++s5) {
      int g = cbase + 4*s5;
      float4 v = (g >= 0) ? *(const float4*)(rowp + g)
                          : make_float4(0.f, 0.f, 0.f, 0.f);
      wr[4*s5+0] = v.x; wr[4*s5+1] = v.y; wr[4*s5+2] = v.z; wr[4*s5+3] = v.w;
    }
    const float Dd = Dv[d];
    #pragma unroll
    for (int k = 0; k < 4; ++k) {
      f32x4 kv0 = *(const f32x4*)&KwS[4*tg + k][0];   // broadcast b128 reads
      f32x4 kv1 = *(const f32x4*)&KwS[4*tg + k][4];
      f32x4 kv2 = *(const f32x4*)&KwS[4*tg + k][8];
      f32x4 kv3 = *(const f32x4*)&KwS[4*tg + k][12];
      float acc = wr[16 + k] * Dd;                    // skip connection u*D
      #pragma unroll
      for (int j = 0; j < 4; ++j)  acc = fmaf(kv0[j], wr[16 + k - j],      acc);
      #pragma unroll
      for (int j = 0; j < 4; ++j)  acc = fmaf(kv1[j], wr[16 + k - (j+4)],  acc);
      #pragma unroll
      for (int j = 0; j < 4; ++j)  acc = fmaf(kv2[j], wr[16 + k - (j+8)],  acc);
      #pragma unroll
      for (int j = 0; j < 4; ++j)  acc = fmaf(kv3[j], wr[16 + k - (j+12)], acc);
      y[c][k] = acc;
      ps[k] = fmaf(acc, acc, ps[k]);
    }
  }

  // ---- RMS reduce over d ----
  #pragma unroll
  for (int k = 0; k < 4; ++k) {
    ps[k] += __shfl_xor(ps[k], 4, 64);
    ps[k] += __shfl_xor(ps[k], 8, 64);
    ps[k] += __shfl_xor(ps[k], 16, 64);
    ps[k] += __shfl_xor(ps[k], 32, 64);
  }
  if (lane < 4)                                 // lane == tg holds t = 4*lane+k
    *(float4*)&SSr[w][4*lane] = make_float4(ps[0], ps[1], ps[2], ps[3]);
  __syncthreads();
  if (tid < 16) {
    float s = 0.f;
    #pragma unroll
    for (int ww = 0; ww < 8; ++ww) s += SSr[ww][tid];
    rsqv[tid] = rsqrtf(s * (1.f/1024.f) + RMS_EPS);
  }
  __syncthreads();

  // ---- normalize + store ----
  float rq[4];
  #pragma unroll
  for (int k = 0; k < 4; ++k) rq[k] = rsqv[4*tg + k];
  #pragma unroll 1
  for (int c = 0; c < 8; ++c) {
    const int d = dr + 128*c;
    const float wn2 = nw[d];
    float4 o;
    o.x = y[c][0] * rq[0] * wn2;
    o.y = y[c][1] * rq[1] * wn2;
    o.z = y[c][2] * rq[2] * wn2;
    o.w = y[c][3] * rq[3] * wn2;
    *(float4*)(ob + (size_t)d * LS + t0 + 4*tg) = o;
  }
}

// ---------------------------------------------------------------------------
extern "C" void kernel_launch(void* const* d_in, const int* in_sizes, int n_in,
                              void* d_out, int out_size, void* d_ws, size_t ws_size,
                              hipStream_t stream) {
  // inputs: [0]=L(int,1), [1]=u, [2]=A, [3]=B, [4]=C, [5]=D, [6]=norm_w
  const float* u  = (const float*)d_in[1];
  const float* A  = (const float*)d_in[2];
  const float* B  = (const float*)d_in[3];
  const float* C  = (const float*)d_in[4];
  const float* Dv = (const float*)d_in[5];
  const float* nw = (const float*)d_in[6];
  float* out = (float*)d_out;

  float* BuCuT = (float*)d_ws;                                        // 4 MB
  unsigned short* Bbf = (unsigned short*)((char*)d_ws + (4u << 20));  // 256 KB

  k0_prep<<<dim3(128), dim3(256), 0, stream>>>(B, C, Bbf);
  kg     <<<dim3(512), dim3(256), 0, stream>>>(u, Bbf, BuCuT);
  kc     <<<dim3(512), dim3(512), 0, stream>>>(u, BuCuT, A, Dv, nw, out);
}